// Round 17
// baseline (324.266 us; speedup 1.0000x reference)
//
#include <hip/hip_runtime.h>
#include <stdint.h>
#include <math.h>

// DeeperGNN forward on MI355X.
// R17 = R16 + k_mlp: GEMM1+LN512+GEMM2+res+LN256 fused per layer (32-row tile,
// barrier-free K-loops, A in LDS, B weights direct from L2). c1b/pstats gone.

typedef __bf16 bf16x8 __attribute__((ext_vector_type(8)));
typedef __bf16 bf16x4 __attribute__((ext_vector_type(4)));
typedef float  f32x4  __attribute__((ext_vector_type(4)));

constexpr int NN   = 16384;   // nodes
constexpr int NE   = 131072;  // edges
constexpr int DIN  = 128;
constexpr int DE   = 64;
constexpr int HD   = 256;
constexpr int HD2  = 512;

__device__ __forceinline__ void gl_lds16(const __bf16* g, __bf16* l) {
  __builtin_amdgcn_global_load_lds((const __attribute__((address_space(1))) void*)g,
                                   (__attribute__((address_space(3))) void*)l, 16, 0, 0);
}

// ---------------- CSR build ----------------
__global__ __launch_bounds__(1024) void k_scan(const int* __restrict__ deg,
                                               int* __restrict__ row_start) {
  __shared__ int part[1024];
  const int t = threadIdx.x;
  const int base = t * 16;
  int loc[16];
  int s = 0;
  #pragma unroll
  for (int i = 0; i < 16; i++) { loc[i] = s; s += deg[base + i]; }
  part[t] = s;
  __syncthreads();
  for (int off = 1; off < 1024; off <<= 1) {
    int v = (t >= off) ? part[t - off] : 0;
    __syncthreads();
    part[t] += v;
    __syncthreads();
  }
  const int excl = (t == 0) ? 0 : part[t - 1];
  #pragma unroll
  for (int i = 0; i < 16; i++) row_start[base + i] = excl + loc[i];
}

__global__ void k_scatter(const int* __restrict__ src, const int* __restrict__ dst,
                          const int* __restrict__ row_start, int* __restrict__ cursor,
                          int2* __restrict__ csr_es) {
  int e = blockIdx.x * 256 + threadIdx.x;
  if (e >= NE) return;
  const int d = dst[e];
  const int p = atomicAdd(&cursor[d], 1);
  csr_es[row_start[d] + p] = make_int2(e, src[e]);
}

// wave-parallel canonical sort
__global__ __launch_bounds__(256)
void k_sortw(const int* __restrict__ row_start, const int* __restrict__ deg,
             int2* __restrict__ csr_es, int* __restrict__ posmap) {
  const int wv   = threadIdx.x >> 6;
  const int lane = threadIdx.x & 63;
  const int node = blockIdx.x * 4 + wv;
  if (node >= NN) return;
  const int st = __builtin_amdgcn_readfirstlane(row_start[node]);
  const int dg = __builtin_amdgcn_readfirstlane(deg[node]);
  if (dg <= 1) {
    if (dg == 1 && lane == 0) posmap[csr_es[st].x] = st;
    return;
  }
  if (dg <= 64) {
    int2 pr = make_int2(0x7fffffff, 0);
    if (lane < dg) pr = csr_es[st + lane];
    int rank = 0;
    for (int j = 0; j < dg; j++) {
      const int ej = __builtin_amdgcn_readlane(pr.x, j);
      if (lane < dg && ej < pr.x) rank++;
    }
    if (lane < dg) {
      csr_es[st + rank] = pr;
      posmap[pr.x] = st + rank;
    }
  } else if (lane == 0) {  // cold fallback
    for (int a = 1; a < dg; a++) {
      int2 k = csr_es[st + a];
      int b = a - 1;
      while (b >= 0 && csr_es[st + b].x > k.x) { csr_es[st + b + 1] = csr_es[st + b]; b--; }
      csr_es[st + b + 1] = k;
    }
    for (int a = 0; a < dg; a++) posmap[csr_es[st + a].x] = st + a;
  }
}

// ---------------- prep: weight transposes + degree histogram ----------------
__global__ void k_prep(const float* __restrict__ enc_w, const float* __restrict__ ee_w,
                       const float* __restrict__ w1, const float* __restrict__ w2,
                       const int* __restrict__ dst, int* __restrict__ deg,
                       __bf16* __restrict__ enc_wT, __bf16* __restrict__ ee_wT,
                       __bf16* __restrict__ w1T, __bf16* __restrict__ w2T) {
  int i = blockIdx.x * 256 + threadIdx.x;
  const int S0 = DIN * HD, S1 = DE * HD, S2 = 4 * HD * HD2, S3 = 4 * HD2 * HD;
  if (i < S0) { int k = i / HD, n = i % HD; enc_wT[n * DIN + k] = (__bf16)enc_w[i]; return; }
  i -= S0;
  if (i < S1) { int k = i / HD, n = i % HD; ee_wT[n * DE + k] = (__bf16)ee_w[i]; return; }
  i -= S1;
  if (i < S2) {
    int l = i / (HD * HD2), r = i % (HD * HD2), k = r / HD2, n = r % HD2;
    w1T[(size_t)l * HD * HD2 + (size_t)n * HD + k] = (__bf16)w1[i]; return;
  }
  i -= S2;
  if (i < S3) {
    int l = i / (HD2 * HD), r = i % (HD2 * HD), k = r / HD, n = r % HD;
    w2T[(size_t)l * HD2 * HD + (size_t)n * HD2 + k] = (__bf16)w2[i]; return;
  }
  i -= S3;
  if (i < NE) { atomicAdd(&deg[dst[i]], 1); return; }
}

// ---------------- encoder GEMM, 128x128 tile, 3-buf counted-vmcnt pipeline ------
template <int RES, int OBF, int STATS, int ESCAT, int AF32>
__global__ __launch_bounds__(256, 3)
void k_gemm(const void* __restrict__ Ap, const __bf16* __restrict__ BT,
            const float* __restrict__ bias, const float* __restrict__ R,
            float* __restrict__ Cf, __bf16* __restrict__ Cb,
            const int* __restrict__ posmap, float2* __restrict__ pstats,
            int M, int Nn, int K) {
  __shared__ __attribute__((aligned(16))) char smem[49152];
  float (*sm)[129] = (float(*)[129])smem;
  float* sbias     = (float*)(smem + 16512);
  float2 (*pst4)[32] = (float2(*)[32])(smem + 17024);
  const __bf16* Ab = (const __bf16*)Ap;
  const float*  Af = (const float*)Ap;
  const int tid  = threadIdx.x;
  const int lane = tid & 63;
  const int wave = tid >> 6;
  const int ntn  = Nn >> 7;
  const int bid  = (int)blockIdx.x;
  const int bn   = (bid >> 3) % ntn;
  const int bm   = (bid & 7) + ((bid >> 3) / ntn) * 8;
  const size_t row0 = (size_t)bm * 128, col0 = (size_t)bn * 128;
  const int wr = (wave >> 1) * 64, wc = (wave & 1) * 64;
  const int ks = lane >> 4, fr = lane & 15;

  auto bufA = [&](int i) -> __bf16* { return (__bf16*)(smem + i * 8192); };
  auto bufB = [&](int i) -> __bf16* { return (__bf16*)(smem + 24576 + i * 8192); };

  f32x4 acc[4][4] = {};

  const int arow = tid >> 2;
  const int aksg = (tid & 3) ^ ((arow >> 1) & 3);

  auto stageB = [&](__bf16* lb, int k0) {
    gl_lds16(BT + (col0 + arow) * K + k0 + aksg * 8, &lb[tid * 8]);
    gl_lds16(BT + (col0 + arow + 64) * K + k0 + aksg * 8, &lb[(tid + 256) * 8]);
  };
  auto stageA = [&](__bf16* la, int k0) {
    gl_lds16(Ab + (row0 + arow) * K + k0 + aksg * 8, &la[tid * 8]);
    gl_lds16(Ab + (row0 + arow + 64) * K + k0 + aksg * 8, &la[(tid + 256) * 8]);
  };
  float4 p0, p1, q0, q1;
  auto loadAf = [&](int k0) {
    const float* a0p = &Af[(row0 + arow) * K + k0 + aksg * 8];
    const float* a1p = &Af[(row0 + arow + 64) * K + k0 + aksg * 8];
    p0 = *(const float4*)a0p; p1 = *(const float4*)(a0p + 4);
    q0 = *(const float4*)a1p; q1 = *(const float4*)(a1p + 4);
  };
  auto writeAf = [&](__bf16* la) {
    bf16x8 o0, o1;
    o0[0] = (__bf16)p0.x; o0[1] = (__bf16)p0.y; o0[2] = (__bf16)p0.z; o0[3] = (__bf16)p0.w;
    o0[4] = (__bf16)p1.x; o0[5] = (__bf16)p1.y; o0[6] = (__bf16)p1.z; o0[7] = (__bf16)p1.w;
    o1[0] = (__bf16)q0.x; o1[1] = (__bf16)q0.y; o1[2] = (__bf16)q0.z; o1[3] = (__bf16)q0.w;
    o1[4] = (__bf16)q1.x; o1[5] = (__bf16)q1.y; o1[6] = (__bf16)q1.z; o1[7] = (__bf16)q1.w;
    *(bf16x8*)&la[tid * 8] = o0;
    *(bf16x8*)&la[(tid + 256) * 8] = o1;
  };

  int slA[4], slB[4];
  #pragma unroll
  for (int m = 0; m < 4; m++) {
    const int rm = wr + m * 16 + fr;
    slA[m] = rm * 4 + (ks ^ ((rm >> 1) & 3));
    const int cn = wc + m * 16 + fr;
    slB[m] = cn * 4 + (ks ^ ((cn >> 1) & 3));
  }

  const int nk = K / 32;
  if (AF32) { loadAf(0); stageB(bufB(0), 0); writeAf(bufA(0)); }
  else      { stageA(bufA(0), 0); stageB(bufB(0), 0); }
  if (nk > 1) {
    if (AF32) { loadAf(32); stageB(bufB(1), 32); writeAf(bufA(1)); }
    else      { stageA(bufA(1), 32); stageB(bufB(1), 32); }
  }
  for (int t = 0; t < nk; t++) {
    const int rem = nk - 1 - t;
    const int nb3 = (t + 2) % 3;
    if (rem >= 2) {
      if (AF32) { loadAf((t + 2) * 32); stageB(bufB(nb3), (t + 2) * 32); }
      else      { stageA(bufA(nb3), (t + 2) * 32); stageB(bufB(nb3), (t + 2) * 32); }
    }
    if (AF32) {
      if (rem >= 2)      asm volatile("s_waitcnt vmcnt(8) lgkmcnt(0)" ::: "memory");
      else if (rem == 1) asm volatile("s_waitcnt vmcnt(2) lgkmcnt(0)" ::: "memory");
      else               asm volatile("s_waitcnt vmcnt(0) lgkmcnt(0)" ::: "memory");
    } else {
      if (rem >= 2)      asm volatile("s_waitcnt vmcnt(8)" ::: "memory");
      else if (rem == 1) asm volatile("s_waitcnt vmcnt(4)" ::: "memory");
      else               asm volatile("s_waitcnt vmcnt(0)" ::: "memory");
    }
    __builtin_amdgcn_s_barrier();
    __builtin_amdgcn_sched_barrier(0);
    const __bf16* la = bufA(t % 3);
    const __bf16* lb = bufB(t % 3);
    bf16x8 af[4], bfr[4];
    #pragma unroll
    for (int m = 0; m < 4; m++) af[m]  = *(const bf16x8*)&la[slA[m] * 8];
    #pragma unroll
    for (int n = 0; n < 4; n++) bfr[n] = *(const bf16x8*)&lb[slB[n] * 8];
    #pragma unroll
    for (int m = 0; m < 4; m++)
      #pragma unroll
      for (int n = 0; n < 4; n++)
        acc[m][n] = __builtin_amdgcn_mfma_f32_16x16x32_bf16(af[m], bfr[n], acc[m][n], 0, 0, 0);
    if (AF32 && rem >= 2) writeAf(bufA(nb3));
    __builtin_amdgcn_s_barrier();
  }
  __syncthreads();

  // ---- coalesced epilogue ----
  if (tid < 128) sbias[tid] = bias[col0 + tid];
  const int rbase = (wave >> 1) * 16 + ks * 4;
  const int rr = tid >> 3, cs = (tid & 7) * 16;
  #pragma unroll
  for (int m = 0; m < 4; m++) {
    if (m) __syncthreads();
    #pragma unroll
    for (int n = 0; n < 4; n++)
      #pragma unroll
      for (int r = 0; r < 4; r++)
        sm[rbase + r][wc + n * 16 + fr] = acc[m][n][r];
    __syncthreads();
    const size_t lrow = ((rr & 16) ? 64 : 0) + m * 16 + (rr & 15);
    const size_t grow = row0 + lrow;
    float v[16];
    #pragma unroll
    for (int j = 0; j < 16; j++) v[j] = sm[rr][cs + j] + sbias[cs + j];
    if (STATS) {
      float ssum = 0.f, ssq = 0.f;
      #pragma unroll
      for (int j = 0; j < 16; j++) { ssum += v[j]; ssq += v[j] * v[j]; }
      #pragma unroll
      for (int o = 1; o < 8; o <<= 1) {
        ssum += __shfl_xor(ssum, o);
        ssq  += __shfl_xor(ssq, o);
      }
      if ((tid & 7) == 0) pst4[m][rr].x = ssum, pst4[m][rr].y = ssq;
    }
    const size_t gbase = grow * Nn + col0 + cs;
    if (RES) {
      #pragma unroll
      for (int j = 0; j < 16; j += 4) {
        const float4 rv = *(const float4*)&R[gbase + j];
        v[j] += rv.x; v[j + 1] += rv.y; v[j + 2] += rv.z; v[j + 3] += rv.w;
      }
    }
    if (OBF == 0 || OBF == 2) {
      #pragma unroll
      for (int j = 0; j < 16; j += 4) {
        float4 o; o.x = v[j]; o.y = v[j + 1]; o.z = v[j + 2]; o.w = v[j + 3];
        *(float4*)&Cf[gbase + j] = o;
      }
    }
    if (OBF == 1 || OBF == 2) {
      const size_t crow = ESCAT ? (size_t)posmap[grow] : grow;
      const size_t cbase = crow * Nn + col0 + cs;
      bf16x8 o0, o1;
      #pragma unroll
      for (int j = 0; j < 8; j++) { o0[j] = (__bf16)v[j]; o1[j] = (__bf16)v[8 + j]; }
      *(bf16x8*)&Cb[cbase] = o0;
      *(bf16x8*)&Cb[cbase + 8] = o1;
    }
  }
  if (STATS) {
    __syncthreads();
    if (tid < 128) {
      const int lr = tid;
      const int hi = lr >> 6, m2 = (lr >> 4) & 3, rl = lr & 15;
      pstats[(row0 + lr) * ntn + bn] = pst4[m2][(hi << 4) | rl];
    }
  }
}

// ---------------- fused layer MLP: 32-row tile ----------------
// phase1: c1 = a1@w1 + b1 (f32 acc), in-register LN512+relu -> a2 (LDS bf16);
// phase2: h = a2@w2 + b2 (+res); epilogue LN256+relu -> zb (+h). Barrier-free
// K-loops: A from LDS (XOR slots), B weights direct global (L2-resident).
template <int RES, int WH>
__global__ __launch_bounds__(256, 2)
void k_mlp(const __bf16* __restrict__ a1, const __bf16* __restrict__ w1T,
           const float* __restrict__ b1v, const float* __restrict__ g1,
           const float* __restrict__ bln1, const __bf16* __restrict__ w2T,
           const float* __restrict__ b2v, const float* __restrict__ R,
           const float* __restrict__ g2, const float* __restrict__ bln2,
           float* __restrict__ hout, __bf16* __restrict__ zout) {
  __shared__ __attribute__((aligned(16))) char smem[60928];
  float* sg1    = (float*)smem;                 // 2048
  float* sb1    = (float*)(smem + 2048);        // 2048
  float* sbias1 = (float*)(smem + 4096);        // 2048
  float* sg2    = (float*)(smem + 6144);        // 1024
  float* sb2    = (float*)(smem + 7168);        // 1024
  float* sbias2 = (float*)(smem + 8192);        // 1024
  float2* wred  = (float2*)(smem + 9216);       // [4][32] = 1024
  float2* lnrow = (float2*)(smem + 10240);      // [32] = 256
  __bf16* a1t   = (__bf16*)(smem + 10496);      // 16384
  __bf16* a2t   = (__bf16*)(smem + 26880);      // 32768 (arena)
  float (*sm)[264] = (float(*)[264])(smem + 26880);  // 33792 (arena overlay)

  const int tid = threadIdx.x, lane = tid & 63, wave = tid >> 6;
  const size_t row0 = (size_t)blockIdx.x * 32;
  const int ks = lane >> 4, fr = lane & 15;

  sg1[tid] = g1[tid];     sg1[tid + 256] = g1[tid + 256];
  sb1[tid] = bln1[tid];   sb1[tid + 256] = bln1[tid + 256];
  sbias1[tid] = b1v[tid]; sbias1[tid + 256] = b1v[tid + 256];
  sg2[tid] = g2[tid]; sb2[tid] = bln2[tid]; sbias2[tid] = b2v[tid];

  // stage a1 tile: slot s holds (r = s>>5, c = (s&31)^(r&31))
  #pragma unroll
  for (int j = 0; j < 4; j++) {
    const int s = j * 256 + tid;
    const int r = s >> 5;
    const int cl = (s & 31) ^ (r & 31);
    gl_lds16(a1 + (row0 + r) * HD + cl * 8, &a1t[s * 8]);
  }
  __syncthreads();

  // ---------- phase 1: c1 = a1 @ w1 + b1 ----------
  f32x4 acc1[2][8] = {};
  {
    auto loadB1 = [&](int t, bf16x8* b) {
      const int k0 = t * 32;
      #pragma unroll
      for (int n = 0; n < 8; n++) {
        const int col = wave * 128 + n * 16 + fr;
        b[n] = *(const bf16x8*)&w1T[(size_t)col * HD + k0 + ks * 8];
      }
    };
    bf16x8 bA[8], bB[8];
    loadB1(0, bA);
    #pragma unroll
    for (int t = 0; t < 8; t++) {
      bf16x8* bc = (t & 1) ? bB : bA;
      bf16x8* bn = (t & 1) ? bA : bB;
      if (t + 1 < 8) loadB1(t + 1, bn);
      bf16x8 af[2];
      #pragma unroll
      for (int m = 0; m < 2; m++) {
        const int rm = m * 16 + fr;
        af[m] = *(const bf16x8*)&a1t[(rm * 32 + ((4 * t + ks) ^ (rm & 31))) * 8];
      }
      #pragma unroll
      for (int m = 0; m < 2; m++)
        #pragma unroll
        for (int n = 0; n < 8; n++)
          acc1[m][n] = __builtin_amdgcn_mfma_f32_16x16x32_bf16(af[m], bc[n], acc1[m][n], 0, 0, 0);
    }
  }
  // fold bias1, row stats (sum, sumsq over 512 cols)
  #pragma unroll
  for (int m = 0; m < 2; m++)
    #pragma unroll
    for (int n = 0; n < 8; n++) {
      const int col = wave * 128 + n * 16 + fr;
      const float bv = sbias1[col];
      #pragma unroll
      for (int r = 0; r < 4; r++) acc1[m][n][r] += bv;
    }
  #pragma unroll
  for (int m = 0; m < 2; m++)
    #pragma unroll
    for (int r = 0; r < 4; r++) {
      float s = 0.f, q = 0.f;
      #pragma unroll
      for (int n = 0; n < 8; n++) { const float v = acc1[m][n][r]; s += v; q += v * v; }
      #pragma unroll
      for (int o = 1; o < 16; o <<= 1) { s += __shfl_xor(s, o); q += __shfl_xor(q, o); }
      if (fr == 0) {
        const int row = m * 16 + ks * 4 + r;
        wred[wave * 32 + row].x = s;
        wred[wave * 32 + row].y = q;
      }
    }
  __syncthreads();
  if (tid < 32) {
    float s = 0.f, q = 0.f;
    #pragma unroll
    for (int w = 0; w < 4; w++) { s += wred[w * 32 + tid].x; q += wred[w * 32 + tid].y; }
    const float mu = s * (1.f / HD2);
    lnrow[tid].x = mu;
    lnrow[tid].y = rsqrtf(q * (1.f / HD2) - mu * mu + 1e-5f);
  }
  __syncthreads();
  // a2 = bf16(relu(LN(c1))) into swizzled LDS tile [row][chunk^(row&63)]
  #pragma unroll
  for (int m = 0; m < 2; m++)
    #pragma unroll
    for (int r = 0; r < 4; r++) {
      const int row = m * 16 + ks * 4 + r;
      const float mu = lnrow[row].x, iv = lnrow[row].y;
      #pragma unroll
      for (int n = 0; n < 8; n++) {
        const int col = wave * 128 + n * 16 + fr;
        const float f = (acc1[m][n][r] - mu) * iv * sg1[col] + sb1[col];
        const int chunk = col >> 3, sub = col & 7;
        a2t[(row * 64 + (chunk ^ (row & 63))) * 8 + sub] = (__bf16)fmaxf(f, 0.f);
      }
    }
  __syncthreads();

  // ---------- phase 2: h = a2 @ w2 + b2 (+res) ----------
  f32x4 acc2[2][4] = {};
  {
    auto loadB2 = [&](int t, bf16x8* b) {
      const int k0 = t * 32;
      #pragma unroll
      for (int n = 0; n < 4; n++) {
        const int col = wave * 64 + n * 16 + fr;
        b[n] = *(const bf16x8*)&w2T[(size_t)col * HD2 + k0 + ks * 8];
      }
    };
    bf16x8 bA[4], bB[4];
    loadB2(0, bA);
    #pragma unroll
    for (int t = 0; t < 16; t++) {
      bf16x8* bc = (t & 1) ? bB : bA;
      bf16x8* bn = (t & 1) ? bA : bB;
      if (t + 1 < 16) loadB2(t + 1, bn);
      bf16x8 af[2];
      #pragma unroll
      for (int m = 0; m < 2; m++) {
        const int rm = m * 16 + fr;
        af[m] = *(const bf16x8*)&a2t[(rm * 64 + ((4 * t + ks) ^ (rm & 63))) * 8];
      }
      #pragma unroll
      for (int m = 0; m < 2; m++)
        #pragma unroll
        for (int n = 0; n < 4; n++)
          acc2[m][n] = __builtin_amdgcn_mfma_f32_16x16x32_bf16(af[m], bc[n], acc2[m][n], 0, 0, 0);
    }
  }
  __syncthreads();   // a2 dead; sm overlays

  // ---------- epilogue: sm transpose, residual, LN256, emit h + zb ----------
  #pragma unroll
  for (int m = 0; m < 2; m++)
    #pragma unroll
    for (int n = 0; n < 4; n++)
      #pragma unroll
      for (int r = 0; r < 4; r++)
        sm[m * 16 + ks * 4 + r][wave * 64 + n * 16 + fr] = acc2[m][n][r];
  __syncthreads();
  const int rr = tid >> 3, c0 = (tid & 7) * 4;
  float v[32];
  float s = 0.f, sq = 0.f;
  #pragma unroll
  for (int j = 0; j < 8; j++) {
    const int c = c0 + j * 32;
    float x0 = sm[rr][c]     + sbias2[c];
    float x1 = sm[rr][c + 1] + sbias2[c + 1];
    float x2 = sm[rr][c + 2] + sbias2[c + 2];
    float x3 = sm[rr][c + 3] + sbias2[c + 3];
    if (RES) {
      const float4 rv = *(const float4*)&R[(row0 + rr) * HD + c];
      x0 += rv.x; x1 += rv.y; x2 += rv.z; x3 += rv.w;
    }
    v[j * 4] = x0; v[j * 4 + 1] = x1; v[j * 4 + 2] = x2; v[j * 4 + 3] = x3;
    s += x0 + x1 + x2 + x3;
    sq += x0 * x0 + x1 * x1 + x2 * x2 + x3 * x3;
  }
  #pragma unroll
  for (int o = 1; o < 8; o <<= 1) { s += __shfl_xor(s, o); sq += __shfl_xor(sq, o); }
  const float mu = s * (1.f / HD);
  const float inv = rsqrtf(sq * (1.f / HD) - mu * mu + 1e-5f);
  #pragma unroll
  for (int j = 0; j < 8; j++) {
    const int c = c0 + j * 32;
    if (WH) {
      float4 o;
      o.x = v[j * 4]; o.y = v[j * 4 + 1]; o.z = v[j * 4 + 2]; o.w = v[j * 4 + 3];
      *(float4*)&hout[(row0 + rr) * HD + c] = o;
    }
    bf16x4 z;
    z[0] = (__bf16)fmaxf((v[j * 4]     - mu) * inv * sg2[c]     + sb2[c],     0.f);
    z[1] = (__bf16)fmaxf((v[j * 4 + 1] - mu) * inv * sg2[c + 1] + sb2[c + 1], 0.f);
    z[2] = (__bf16)fmaxf((v[j * 4 + 2] - mu) * inv * sg2[c + 2] + sb2[c + 2], 0.f);
    z[3] = (__bf16)fmaxf((v[j * 4 + 3] - mu) * inv * sg2[c + 3] + sb2[c + 3], 0.f);
    *(bf16x4*)&zout[(row0 + rr) * HD + c] = z;
  }
}

// ---------------- wave-per-node softmax aggregation (8-deep groups, bf16 zb) ----
__global__ __launch_bounds__(256)
void k_msg(const __bf16* __restrict__ zb, const __bf16* __restrict__ ecsr,
           const int* __restrict__ row_start, const int* __restrict__ deg,
           const int2* __restrict__ csr_es, const float* __restrict__ tvec,
           int layer, __bf16* __restrict__ a1) {
  const int wv   = __builtin_amdgcn_readfirstlane(threadIdx.x >> 6);
  const int lane = threadIdx.x & 63;
  const int node = blockIdx.x * 4 + wv;
  const int st = __builtin_amdgcn_readfirstlane(row_start[node]);
  const int dg = __builtin_amdgcn_readfirstlane(deg[node]);
  const float t = tvec[layer];
  const int f0 = lane * 4;

  int my_src = 0;
  if (lane < dg) my_src = csr_es[st + lane].y;
  const bf16x4 sv = *(const bf16x4*)&zb[(size_t)node * HD + f0];

  float den[4] = {0.f, 0.f, 0.f, 0.f}, agg[4] = {0.f, 0.f, 0.f, 0.f};
  const int dmain = dg < 64 ? dg : 64;
  int j = 0;
  for (; j + 8 <= dmain; j += 8) {
    bf16x4 zv[8], ev[8];
    #pragma unroll
    for (int u = 0; u < 8; u++) {
      const int sn = __builtin_amdgcn_readlane(my_src, j + u);
      zv[u] = *(const bf16x4*)&zb[(size_t)sn * HD + f0];
      ev[u] = *(const bf16x4*)&ecsr[(size_t)(st + j + u) * HD + f0];
    }
    #pragma unroll
    for (int u = 0; u < 8; u++)
      #pragma unroll
      for (int q = 0; q < 4; q++) {
        const float m  = fmaxf((float)zv[u][q] + (float)ev[u][q], 0.f) + 1e-7f;
        const float ex = __expf(m * t);
        den[q] += ex;
        agg[q] += m * ex;
      }
  }
  for (; j + 4 <= dmain; j += 4) {
    bf16x4 zv[4], ev[4];
    #pragma unroll
    for (int u = 0; u < 4; u++) {
      const int sn = __builtin_amdgcn_readlane(my_src, j + u);
      zv[u] = *(const bf16x4*)&zb[(size_t)sn * HD + f0];
      ev[u] = *(const bf16x4*)&ecsr[(size_t)(st + j + u) * HD + f0];
    }
    #pragma unroll
    for (int u = 0; u < 4; u++)
      #pragma unroll
      for (int q = 0; q < 4; q++) {
        const float m  = fmaxf((float)zv[u][q] + (float)ev[u][q], 0.f) + 1e-7f;
        const float ex = __expf(m * t);
        den[q] += ex;
        agg[q] += m * ex;
      }
  }
  for (; j < dmain; j++) {
    const int sn = __builtin_amdgcn_readlane(my_src, j);
    const bf16x4 zv = *(const bf16x4*)&zb[(size_t)sn * HD + f0];
    const bf16x4 ev = *(const bf16x4*)&ecsr[(size_t)(st + j) * HD + f0];
    #pragma unroll
    for (int q = 0; q < 4; q++) {
      const float m  = fmaxf((float)zv[q] + (float)ev[q], 0.f) + 1e-7f;
      const float ex = __expf(m * t);
      den[q] += ex;
      agg[q] += m * ex;
    }
  }
  for (int jj = 64; jj < dg; jj++) {  // cold path
    const int2 pr = csr_es[st + jj];
    const bf16x4 zv = *(const bf16x4*)&zb[(size_t)pr.y * HD + f0];
    const bf16x4 ev = *(const bf16x4*)&ecsr[(size_t)(st + jj) * HD + f0];
    #pragma unroll
    for (int q = 0; q < 4; q++) {
      const float m  = fmaxf((float)zv[q] + (float)ev[q], 0.f) + 1e-7f;
      const float ex = __expf(m * t);
      den[q] += ex;
      agg[q] += m * ex;
    }
  }
  bf16x4 r;
  #pragma unroll
  for (int q = 0; q < 4; q++) {
    const float res = (dg > 0) ? agg[q] / (den[q] + 1e-16f) : 0.f;
    r[q] = (__bf16)(res + (float)sv[q]);
  }
  *(bf16x4*)&a1[(size_t)node * HD + f0] = r;
}

// ---------------- head: out = zb @ lin_w + lin_b ----------------
__global__ __launch_bounds__(256)
void k_head(const __bf16* __restrict__ zb, const float* __restrict__ lw,
            const float* __restrict__ lb, float* __restrict__ out) {
  __shared__ float slw[256 * 16];     // [k][c]
  __shared__ __bf16 srow[16 * 256];
  const int t = threadIdx.x;
  const size_t row0 = (size_t)blockIdx.x * 16;
  #pragma unroll
  for (int j = 0; j < 16; j++) slw[j * 256 + t] = lw[j * 256 + t];
  #pragma unroll
  for (int j = 0; j < 2; j++) {
    const int c = j * 256 + t;
    ((bf16x8*)srow)[c] = ((const bf16x8*)(zb + row0 * 256))[c];
  }
  __syncthreads();
  const int rl = t >> 4, col = t & 15;
  float s = lb[col];
  for (int k0 = 0; k0 < 256; k0 += 8) {
    const bf16x8 zv = *(const bf16x8*)&srow[rl * 256 + k0];
    #pragma unroll
    for (int q = 0; q < 8; q++) s += (float)zv[q] * slw[(k0 + q) * 16 + col];
  }
  out[(row0 + rl) * 16 + col] = s;
}

// ---------------- host launch ----------------
extern "C" void kernel_launch(void* const* d_in, const int* in_sizes, int n_in,
                              void* d_out, int out_size, void* d_ws, size_t ws_size,
                              hipStream_t stream) {
  const float* x     = (const float*)d_in[0];
  const int*   ei    = (const int*)d_in[1];
  const float* ea    = (const float*)d_in[2];
  const float* enc_w = (const float*)d_in[3];
  const float* enc_b = (const float*)d_in[4];
  const float* ee_w  = (const float*)d_in[5];
  const float* ee_b  = (const float*)d_in[6];
  const float* w1    = (const float*)d_in[7];
  const float* b1    = (const float*)d_in[8];
  const float* lng   = (const float*)d_in[9];
  const float* lnb   = (const float*)d_in[10];
  const float* w2    = (const float*)d_in[11];
  const float* b2    = (const float*)d_in[12];
  const float* tvec  = (const float*)d_in[13];
  const float* ng    = (const float*)d_in[14];
  const float* nb    = (const float*)d_in[15];
  const float* lin_w = (const float*)d_in[16];
  const float* lin_b = (const float*)d_in[17];

  uint8_t* p = (uint8_t*)d_ws;
  auto alloc = [&](size_t bytes) { uint8_t* r = p; p += (bytes + 255) & ~(size_t)255; return r; };
  __bf16* e_csr  = (__bf16*)alloc((size_t)NE * HD * 2);
  float*  h      = (float*) alloc((size_t)NN * HD * 4);
  __bf16* hb     = (__bf16*)alloc((size_t)NN * HD * 2);
  __bf16* zb     = (__bf16*)alloc((size_t)NN * HD * 2);
  __bf16* a1     = (__bf16*)alloc((size_t)NN * HD * 2);
  __bf16* enc_wT = (__bf16*)alloc((size_t)HD * DIN * 2);
  __bf16* ee_wT  = (__bf16*)alloc((size_t)HD * DE * 2);
  __bf16* w1T    = (__bf16*)alloc((size_t)4 * HD2 * HD * 2);
  __bf16* w2T    = (__bf16*)alloc((size_t)4 * HD * HD2 * 2);
  int* deg       = (int*)alloc((size_t)NN * 4);
  int* cursor    = (int*)alloc((size_t)NN * 4);   // contiguous with deg -> one memset
  int* row_start = (int*)alloc((size_t)NN * 4);
  int* posmap    = (int*)alloc((size_t)NE * 4);
  int2* csr_es   = (int2*)alloc((size_t)NE * 8);

  const int* srcp = ei;
  const int* dstp = ei + NE;

  hipMemsetAsync(deg, 0, (size_t)NN * 8, stream);  // deg + cursor

  const int prep_total = DIN * HD + DE * HD + 4 * HD * HD2 + 4 * HD2 * HD + NE;
  k_prep<<<(prep_total + 255) / 256, 256, 0, stream>>>(enc_w, ee_w, w1, w2, dstp, deg,
                                                       enc_wT, ee_wT, w1T, w2T);
  k_scan<<<1, 1024, 0, stream>>>(deg, row_start);
  k_scatter<<<NE / 256, 256, 0, stream>>>(srcp, dstp, row_start, cursor, csr_es);
  k_sortw<<<NN / 4, 256, 0, stream>>>(row_start, deg, csr_es, posmap);

  // node encoder: h(f32) + hb(bf16) = x @ enc_w + enc_b  (f32 A direct)
  k_gemm<0, 2, 0, 0, 1><<<(NN / 128) * (HD / 128), 256, 0, stream>>>(
      x, enc_wT, enc_b, nullptr, h, hb, nullptr, nullptr, NN, HD, DIN);
  // edge encoder -> e_csr (CSR-position-ordered rows), f32 A direct
  k_gemm<0, 1, 0, 1, 1><<<(NE / 128) * (HD / 128), 256, 0, stream>>>(
      ea, ee_wT, ee_b, nullptr, nullptr, e_csr, posmap, nullptr, NE, HD, DE);

  for (int i = 0; i < 4; i++) {
    const __bf16* zin = (i == 0) ? hb : zb;
    k_msg<<<NN / 4, 256, 0, stream>>>(zin, e_csr, row_start, deg, csr_es, tvec, i, a1);
    const int nidx = (i < 3) ? i + 1 : 0;
    const float* gg = ng + (size_t)nidx * HD;
    const float* bb = nb + (size_t)nidx * HD;
    if (i == 0)
      k_mlp<0, 1><<<NN / 32, 256, 0, stream>>>(
          a1, w1T + (size_t)i * HD2 * HD, b1 + (size_t)i * HD2,
          lng + (size_t)i * HD2, lnb + (size_t)i * HD2,
          w2T + (size_t)i * HD * HD2, b2 + (size_t)i * HD,
          nullptr, gg, bb, h, zb);
    else if (i < 3)
      k_mlp<1, 1><<<NN / 32, 256, 0, stream>>>(
          a1, w1T + (size_t)i * HD2 * HD, b1 + (size_t)i * HD2,
          lng + (size_t)i * HD2, lnb + (size_t)i * HD2,
          w2T + (size_t)i * HD * HD2, b2 + (size_t)i * HD,
          h, gg, bb, h, zb);
    else
      k_mlp<1, 0><<<NN / 32, 256, 0, stream>>>(
          a1, w1T + (size_t)i * HD2 * HD, b1 + (size_t)i * HD2,
          lng + (size_t)i * HD2, lnb + (size_t)i * HD2,
          w2T + (size_t)i * HD * HD2, b2 + (size_t)i * HD,
          h, gg, bb, h, zb);
  }

  k_head<<<NN / 16, 256, 0, stream>>>(zb, lin_w, lin_b, (float*)d_out);
}